// Round 15
// baseline (259.639 us; speedup 1.0000x reference)
//
#include <hip/hip_runtime.h>
#include <hip/hip_bf16.h>

// FeastNet fused: B=2, V=50000, NB=16, C=64, K=8, O=64
// out[b,v,o] = inv_deg[v] * sum_{c,k} M[c,k] * W[c,k,o]
//   M[c,k]   = sum_n patches[b,v,n,c] * q[b,v,n,k]
//   q        = softmax_k( xu[self] - xu[neighbor] ),  xu = x @ u
// v7: TV=8, 32 threads/vertex, 2 channels/thread (float2 gathers), depth-8
// prefetch. Live set ~58 regs -> fits the 64-reg granule (8 waves/SIMD).
// R13/R14 evidence: allocator clamps at 64 and spills anything bigger;
// occupancy (9-12 waves) is the concurrency limiter (Little's law matches
// 3.3 TB/s). Canary: VGPR=64 AND WRITE_SIZE~25MB simultaneously.

constexpr int BB = 2;
constexpr int VV = 50000;
#define NB 16
#define CC 64
#define KK 8
#define OO 64
#define TV 8  // vertices per workgroup (256 threads, 32 threads/vertex)

typedef __attribute__((ext_vector_type(8))) short bf16x8;  // 8 bf16 (4 VGPRs)
typedef __attribute__((ext_vector_type(4))) float f32x4;

static __device__ __forceinline__ short f2b(float f) {
    __hip_bfloat16 h = __float2bfloat16(f);  // RNE
    return *reinterpret_cast<short*>(&h);
}

// ---- K0 merged prep: xu (blocks [0,XUB)) + Wb prep (blocks [XUB, XUB+WPB)) ----
constexpr int XUB = (BB * VV * 2 + 255) / 256;  // 2 threads per row -> 782
constexpr int WPB = (CC * KK * OO) / 256;       // 128

__global__ void prep_kernel(const float* __restrict__ x,
                            const float* __restrict__ u,
                            float* __restrict__ xu,
                            const float* __restrict__ W,
                            short* __restrict__ Wb) {
    int blk = blockIdx.x;
    if (blk < XUB) {
        // xu[g,k] = sum_c x[g,c]*u[c,k]; thread = (row g, k-half)
        int t = blk * 256 + threadIdx.x;
        if (t >= BB * VV * 2) return;
        int g = t >> 1, half = t & 1;
        const float4* xr =
            reinterpret_cast<const float4*>(x) + (size_t)g * (CC / 4);
        const float4* u4 = reinterpret_cast<const float4*>(u);
        float a0 = 0.f, a1 = 0.f, a2 = 0.f, a3 = 0.f;
#pragma unroll
        for (int c4 = 0; c4 < CC / 4; ++c4) {
            float4 xv = xr[c4];
            float4 u0 = u4[(c4 * 4 + 0) * 2 + half];
            float4 u1 = u4[(c4 * 4 + 1) * 2 + half];
            float4 u2 = u4[(c4 * 4 + 2) * 2 + half];
            float4 u3 = u4[(c4 * 4 + 3) * 2 + half];
            a0 = fmaf(xv.x, u0.x, a0); a1 = fmaf(xv.x, u0.y, a1);
            a2 = fmaf(xv.x, u0.z, a2); a3 = fmaf(xv.x, u0.w, a3);
            a0 = fmaf(xv.y, u1.x, a0); a1 = fmaf(xv.y, u1.y, a1);
            a2 = fmaf(xv.y, u1.z, a2); a3 = fmaf(xv.y, u1.w, a3);
            a0 = fmaf(xv.z, u2.x, a0); a1 = fmaf(xv.z, u2.y, a1);
            a2 = fmaf(xv.z, u2.z, a2); a3 = fmaf(xv.z, u2.w, a3);
            a0 = fmaf(xv.w, u3.x, a0); a1 = fmaf(xv.w, u3.y, a1);
            a2 = fmaf(xv.w, u3.z, a2); a3 = fmaf(xv.w, u3.w, a3);
        }
        reinterpret_cast<float4*>(xu)[(size_t)g * 2 + half] =
            make_float4(a0, a1, a2, a3);
    } else {
        // W (C,K*O) f32 -> Wb bf16 in MFMA B-fragment order.
        // Wb[((ks*4+gct)*64+l)*8+e] = W[(ks*32+(l>>4)*8+e)*OO + gct*16+(l&15)]
        int dst = (blk - XUB) * 256 + threadIdx.x;
        int e = dst & 7;
        int l = (dst >> 3) & 63;
        int ctk = dst >> 9;
        int gct = ctk & 3;
        int ks = ctk >> 2;
        int ck = ks * 32 + (l >> 4) * 8 + e;
        int o = gct * 16 + (l & 15);
        Wb[dst] = f2b(W[ck * OO + o]);
    }
}

// ---------------- K2: fused q + M-build + MFMA contraction ----------------
__global__ __launch_bounds__(256, 8) void feast_fused(
    const float* __restrict__ x, const int* __restrict__ adj,
    const float* __restrict__ xu, const short* __restrict__ Wb,
    float* __restrict__ out) {
    // 16KB, two lives: (1) qlds fp32 [n=16][vl=8][k=8] = 4KB at offset 0;
    // (2) M bf16 [8][512] in rows 0..7 (row = 1024B, 64 slots, swizzled).
    // Phase-2 MFMA reads rows 0..15; rows 8..15 are garbage and pollute
    // only C rows 8..15, which are never stored.
    __shared__ char smem[16 * 1024];
    __shared__ float sInvd[TV];

    int t = threadIdx.x;
    int b = blockIdx.y;
    int v0 = blockIdx.x * TV;
    int vl = t >> 5;  // vertex local 0..7
    int jj = t & 31;  // channel-pair idx 0..31 (channels 2jj, 2jj+1)
    int v = v0 + vl;  // VV % TV == 0: always valid

    float* qlds = reinterpret_cast<float*>(smem);
    const float4* xu4 = reinterpret_cast<const float4*>(xu);
    const float2* x2 = reinterpret_cast<const float2*>(x);

    // ---- adj row -> float2-offsets off[16]; adj values die here ----
    int off[NB];
    float deg = 0.f;
    {
        const int4* arow = reinterpret_cast<const int4*>(adj + (size_t)v * NB);
#pragma unroll
        for (int n4 = 0; n4 < 4; ++n4) {
            int4 t4 = arow[n4];
            int aa[4] = {t4.x, t4.y, t4.z, t4.w};
#pragma unroll
            for (int s = 0; s < 4; ++s) {
                int an = aa[s];
                deg += (an != 0) ? 1.f : 0.f;
                off[n4 * 4 + s] = (b * VV + (an ? an - 1 : 0)) * 32 + jj;
            }
        }
    }
    if (jj == 0) sInvd[vl] = (deg > 0.f) ? (1.f / deg) : 0.f;

    // ---- Phase A (waves 0-1): q for (vertex t>>4, neighbor t&15) ----
    if (t < 128) {
        int pav = t >> 4;  // 0..7
        int pan = t & 15;  // 0..15
        int pv = v0 + pav;
        int gs = b * VV + pv;
        float4 s0 = xu4[(size_t)gs * 2], s1 = xu4[(size_t)gs * 2 + 1];
        int an = adj[(size_t)pv * NB + pan];
        int g = b * VV + (an ? an - 1 : 0);
        float4 n0 = xu4[(size_t)g * 2], n1 = xu4[(size_t)g * 2 + 1];
        float l8[KK] = {s0.x - n0.x, s0.y - n0.y, s0.z - n0.z, s0.w - n0.w,
                        s1.x - n1.x, s1.y - n1.y, s1.z - n1.z, s1.w - n1.w};
        float mx = l8[0];
#pragma unroll
        for (int k = 1; k < KK; ++k) mx = fmaxf(mx, l8[k]);
        float e8[KK];
        float sum = 0.f;
#pragma unroll
        for (int k = 0; k < KK; ++k) {
            e8[k] = __expf(l8[k] - mx);
            sum += e8[k];
        }
        float r = an ? (1.f / sum) : 0.f;
        f32x4* qp = reinterpret_cast<f32x4*>(qlds + pan * 64 + pav * 8);
        qp[0] = (f32x4){e8[0] * r, e8[1] * r, e8[2] * r, e8[3] * r};
        qp[1] = (f32x4){e8[4] * r, e8[5] * r, e8[6] * r, e8[7] * r};
    }

// ---- Phase C: acc[c=2][k=8] over 16 neighbors, depth-8 prefetch ----
#define CONS(n, P)                                                             \
    {                                                                          \
        const f32x4* qv =                                                      \
            reinterpret_cast<const f32x4*>(qlds + (n) * 64 + vl * 8);          \
        f32x4 q0 = qv[0];                                                      \
        f32x4 q1 = qv[1];                                                      \
        _Pragma("unroll") for (int k = 0; k < 4; ++k) {                        \
            acc[0][k] = fmaf(P.x, q0[k], acc[0][k]);                           \
            acc[0][k + 4] = fmaf(P.x, q1[k], acc[0][k + 4]);                   \
            acc[1][k] = fmaf(P.y, q0[k], acc[1][k]);                           \
            acc[1][k + 4] = fmaf(P.y, q1[k], acc[1][k + 4]);                   \
        }                                                                      \
    }

    float2 P0, P1, P2, P3, P4, P5, P6, P7;
    P0 = x2[off[0]];
    P1 = x2[off[1]];
    P2 = x2[off[2]];
    P3 = x2[off[3]];
    P4 = x2[off[4]];
    P5 = x2[off[5]];
    P6 = x2[off[6]];
    P7 = x2[off[7]];
    __syncthreads();  // qlds visible; 8 gathers in flight across the barrier

    float acc[2][KK];
#pragma unroll
    for (int c = 0; c < 2; ++c)
#pragma unroll
        for (int k = 0; k < KK; ++k) acc[c][k] = 0.f;

    CONS(0, P0) P0 = x2[off[8]];
    CONS(1, P1) P1 = x2[off[9]];
    CONS(2, P2) P2 = x2[off[10]];
    CONS(3, P3) P3 = x2[off[11]];
    CONS(4, P4) P4 = x2[off[12]];
    CONS(5, P5) P5 = x2[off[13]];
    CONS(6, P6) P6 = x2[off[14]];
    CONS(7, P7) P7 = x2[off[15]];
    CONS(8, P0)
    CONS(9, P1)
    CONS(10, P2)
    CONS(11, P3)
    CONS(12, P4)
    CONS(13, P5)
    CONS(14, P6)
    CONS(15, P7)

    __syncthreads();  // all q reads done -> safe to overwrite smem with M

    // ---- M -> bf16 LDS rows 0..7; slot = channel (2jj, 2jj+1);
    //      swizzle slot2 = slot ^ ((slot>>3)&7) ^ (row&7) (same on read)
#pragma unroll
    for (int s = 0; s < 2; ++s) {
        bf16x8 w;
#pragma unroll
        for (int k = 0; k < KK; ++k) w[k] = f2b(acc[s][k]);
        int slot = 2 * jj + s;
        int slot2 = slot ^ ((slot >> 3) & 7) ^ (vl & 7);
        *reinterpret_cast<bf16x8*>(smem + vl * 1024 + slot2 * 16) = w;
    }
    __syncthreads();

    // ---- Phase 2: out[8x64] = M[8x512] @ Wb[512x64] via MFMA (16-row op,
    //      rows 8..15 garbage -> their C rows discarded) ----
    {
        int wid = t >> 6;  // wave 0..3 = col tile (16 cols each)
        int l = t & 63;
        int r = l & 15;  // A-frag row

        f32x4 acc2 = (f32x4){0.f, 0.f, 0.f, 0.f};
        const bf16x8* WbV = reinterpret_cast<const bf16x8*>(Wb);

#pragma unroll
        for (int ks = 0; ks < 16; ++ks) {
            int ks4h = ks * 4 + (l >> 4);
            int slotA = ks4h ^ ((ks4h >> 3) & 7) ^ (r & 7);
            bf16x8 afrag = *reinterpret_cast<const bf16x8*>(
                smem + r * 1024 + slotA * 16);
            bf16x8 bfrag = WbV[(ks * 4 + wid) * 64 + l];
            acc2 = __builtin_amdgcn_mfma_f32_16x16x32_bf16(afrag, bfrag, acc2,
                                                           0, 0, 0);
        }

        // C/D layout: col = l&15, row = (l>>4)*4 + reg; keep rows 0..7
        int col = wid * 16 + (l & 15);
#pragma unroll
        for (int jr = 0; jr < 4; ++jr) {
            int rowl = (l >> 4) * 4 + jr;
            if (rowl < TV) {
                out[((size_t)b * VV + v0 + rowl) * OO + col] =
                    acc2[jr] * sInvd[rowl];
            }
        }
    }
}

extern "C" void kernel_launch(void* const* d_in, const int* in_sizes, int n_in,
                              void* d_out, int out_size, void* d_ws,
                              size_t ws_size, hipStream_t stream) {
    const float* x = (const float*)d_in[0];  // (B,V,C) f32
    const float* u = (const float*)d_in[1];  // (C,K)   f32
    const float* W = (const float*)d_in[2];  // (C,K*O) f32
    const int* adj = (const int*)d_in[3];    // (V,NB)  i32
    float* out = (float*)d_out;              // (B,V,O) f32

    float* xu = (float*)d_ws;  // (B*V, K) f32 = 3.2 MB
    short* Wb = (short*)((char*)d_ws + (size_t)BB * VV * KK * sizeof(float));

    prep_kernel<<<XUB + WPB, 256, 0, stream>>>(x, u, xu, W, Wb);
    dim3 g(VV / TV, BB);
    feast_fused<<<g, 256, 0, stream>>>(x, adj, xu, Wb, out);
}